// Round 10
// baseline (160.321 us; speedup 1.0000x reference)
//
#include <hip/hip_runtime.h>

#define B_DIM 4096
#define L_DIM 4096
#define SEGLEN 256
#define NSEG (L_DIM / SEGLEN)   // 16
#define WARM 512                // proven coupling window (r5/6/8 absmax 0)
#define CHUNK 16                // time steps per LDS chunk
#define RPB 256                 // rows per block = 4 chains per lane

typedef float f4 __attribute__((ext_vector_type(4)));
typedef int i4 __attribute__((ext_vector_type(4)));

// ws: float C_acc[4096], float ts_acc[4096], int first_acc[4096]
__global__ __launch_bounds__(256) void init_kernel(float* wsf, int* wsi) {
    int i = blockIdx.x * 256 + threadIdx.x;
    if (i < 2 * B_DIM) wsf[i] = 0.f;
    if (i < B_DIM) wsi[i] = L_DIM;
}

__device__ __forceinline__ void dma16(const float* g, float* l) {
    __builtin_amdgcn_global_load_lds(
        (const __attribute__((address_space(1))) unsigned int*)g,
        (__attribute__((address_space(3))) unsigned int*)l, 16, 0, 0);
}

// Stage-major 4-chain LIF step on f4 (chains = 4 rows at the same timestep).
// Each f4 op lowers to 4 ADJACENT independent VALU instrs -> one ~85cyc chain
// latency is shared by 4 chain-steps. Math identical to proven scalar version:
// q = RN(u/20) Markstein; u' = sp_prev ? I : (u-q)+I  [reset == I exactly].
#define CORE4(IV)                                      \
    {                                                  \
        f4 q0 = u4 * kC;                               \
        f4 rr = __builtin_elementwise_fma(kN20, q0, u4); \
        f4 q  = __builtin_elementwise_fma(rr, kC, q0); \
        f4 a  = u4 - q;                                \
        f4 b  = a + (IV);                              \
        u4 = sp4 ? (IV) : b;                           \
        sp4 = (u4 >= kTh);                             \
    }

#define FULL4(IV, SFOUT)                               \
    {                                                  \
        CORE4(IV)                                      \
        SFOUT = sp4 ? kOne : kZero;                    \
        cnt4 += SFOUT;                                 \
        seen4 = __builtin_elementwise_max(seen4, SFOUT); \
        accS4 += cnt4;                                 \
        accF4 += seen4;                                \
    }

// Single wave per block; 4 chains/lane (rows lane+{0,64,128,192}); 1 block/CU.
// Iter order: gate(DMA(c)) -> ds_read chunk c -> pin -> issue DMA(c+1) ->
// compute. Gate: after a warm iter only DMA(c) is outstanding -> vmcnt(0);
// after an emit iter the 16 stores sit behind DMA(c) -> vmcnt(16).
__global__ __launch_bounds__(64, 1) void lif_kernel(const float* __restrict__ I,
                                                    float* __restrict__ out,
                                                    float* __restrict__ Cacc,
                                                    float* __restrict__ tsAcc,
                                                    int* __restrict__ firstAcc) {
    __shared__ __align__(16) float lds[2][RPB * CHUNK];  // 2 x 16 KB
    const int lane = threadIdx.x;
    const int grp = blockIdx.x & 15;   // 16 row groups of 256
    const int seg = blockIdx.x >> 4;   // 16 segments
    const int rowBase = grp * RPB;
    const int t0 = seg * SEGLEN;
    const int start = (t0 >= WARM) ? (t0 - WARM) : 0;  // segs 0,1 exact from t=0
    const int nwarmCh = (t0 - start) / CHUNK;
    const int nch = nwarmCh + SEGLEN / CHUNK;

    // DMA map (verified r9): instr p covers rows p*16+(lane>>2); lane writes
    // LDS f4-slot lane + p*64; slot s of row r holds granule s^(r&3).
    const float* psrc = I + (size_t)(rowBase + (lane >> 2)) * L_DIM + start +
                        (((lane & 3) ^ ((lane >> 2) & 3)) << 2);

#define DMA_CHUNK(BUFI, CC)                                           \
    {                                                                 \
        float* ldst = &lds[BUFI][0] + (lane << 2);                    \
        const float* gsrc = psrc + (size_t)(CC) * CHUNK;              \
        _Pragma("unroll")                                             \
        for (int p = 0; p < 16; ++p)                                  \
            dma16(gsrc + (size_t)(p * 16) * L_DIM, ldst + p * 256);   \
    }

    const f4 kC = 0.05f, kN20 = -20.0f, kTh = 1.0f, kOne = 1.0f, kZero = 0.0f;
    f4 u4 = 0.0f, cnt4 = 0.0f, seen4 = 0.0f, accS4 = 0.0f, accF4 = 0.0f;
    i4 sp4 = 0;

    const int row0 = rowBase + lane;
    float* so0 = out + (size_t)row0 * L_DIM + t0;
    float* so1 = so0 + (size_t)64 * L_DIM;
    float* so2 = so0 + (size_t)128 * L_DIM;
    float* so3 = so0 + (size_t)192 * L_DIM;

    const int lbase = lane << 4;  // lane*16 floats
    const int rot = lane & 3;
    const int o0 = ((0 ^ rot) << 2), ofs1 = ((1 ^ rot) << 2);
    const int o2 = ((2 ^ rot) << 2), ofs3 = ((3 ^ rot) << 2);

    DMA_CHUNK(0, 0)
    for (int c = 0; c < nch; ++c) {
        if (c > nwarmCh)
            asm volatile("s_waitcnt vmcnt(16)" ::: "memory");
        else
            asm volatile("s_waitcnt vmcnt(0)" ::: "memory");

        const float* buf = &lds[c & 1][0];
        // chain j granule g at: j*1024 + lbase + ((g^rot)<<2)   (floats)
        f4 v00 = *(const f4*)(buf + lbase + o0);
        f4 v01 = *(const f4*)(buf + lbase + ofs1);
        f4 v02 = *(const f4*)(buf + lbase + o2);
        f4 v03 = *(const f4*)(buf + lbase + ofs3);
        f4 v10 = *(const f4*)(buf + 1024 + lbase + o0);
        f4 v11 = *(const f4*)(buf + 1024 + lbase + ofs1);
        f4 v12 = *(const f4*)(buf + 1024 + lbase + o2);
        f4 v13 = *(const f4*)(buf + 1024 + lbase + ofs3);
        f4 v20 = *(const f4*)(buf + 2048 + lbase + o0);
        f4 v21 = *(const f4*)(buf + 2048 + lbase + ofs1);
        f4 v22 = *(const f4*)(buf + 2048 + lbase + o2);
        f4 v23 = *(const f4*)(buf + 2048 + lbase + ofs3);
        f4 v30 = *(const f4*)(buf + 3072 + lbase + o0);
        f4 v31 = *(const f4*)(buf + 3072 + lbase + ofs1);
        f4 v32 = *(const f4*)(buf + 3072 + lbase + o2);
        f4 v33 = *(const f4*)(buf + 3072 + lbase + ofs3);
        asm volatile("" : "+v"(v00), "+v"(v01), "+v"(v02), "+v"(v03),
                         "+v"(v10), "+v"(v11), "+v"(v12), "+v"(v13),
                         "+v"(v20), "+v"(v21), "+v"(v22), "+v"(v23),
                         "+v"(v30), "+v"(v31), "+v"(v32), "+v"(v33));

        if (c + 1 < nch) DMA_CHUNK((c + 1) & 1, c + 1)

        if (c < nwarmCh) {
#define WARMG(A, Bv, Cv, D)                                           \
            { f4 iv;                                                  \
              iv = (f4){A.x, Bv.x, Cv.x, D.x}; CORE4(iv)              \
              iv = (f4){A.y, Bv.y, Cv.y, D.y}; CORE4(iv)              \
              iv = (f4){A.z, Bv.z, Cv.z, D.z}; CORE4(iv)              \
              iv = (f4){A.w, Bv.w, Cv.w, D.w}; CORE4(iv) }
            WARMG(v00, v10, v20, v30) WARMG(v01, v11, v21, v31)
            WARMG(v02, v12, v22, v32) WARMG(v03, v13, v23, v33)
#undef WARMG
        } else {
            const int co = (c - nwarmCh) * CHUNK;
#define EMITG(A, Bv, Cv, D, G)                                        \
            { f4 iv, sfx, sfy, sfz, sfw;                              \
              iv = (f4){A.x, Bv.x, Cv.x, D.x}; FULL4(iv, sfx)         \
              iv = (f4){A.y, Bv.y, Cv.y, D.y}; FULL4(iv, sfy)         \
              iv = (f4){A.z, Bv.z, Cv.z, D.z}; FULL4(iv, sfz)         \
              iv = (f4){A.w, Bv.w, Cv.w, D.w}; FULL4(iv, sfw)         \
              f4 s0 = (f4){sfx.x, sfy.x, sfz.x, sfw.x};               \
              f4 s1 = (f4){sfx.y, sfy.y, sfz.y, sfw.y};               \
              f4 s2 = (f4){sfx.z, sfy.z, sfz.z, sfw.z};               \
              f4 s3 = (f4){sfx.w, sfy.w, sfz.w, sfw.w};               \
              *(f4*)(so0 + co + 4 * (G)) = s0;                        \
              *(f4*)(so1 + co + 4 * (G)) = s1;                        \
              *(f4*)(so2 + co + 4 * (G)) = s2;                        \
              *(f4*)(so3 + co + 4 * (G)) = s3; }
            EMITG(v00, v10, v20, v30, 0) EMITG(v01, v11, v21, v31, 1)
            EMITG(v02, v12, v22, v32, 2) EMITG(v03, v13, v23, v33, 3)
#undef EMITG
        }
    }

    // per-segment partials: exact integers < 2^24 -> float atomics exact
#define TAIL(CN, AF, AS, ROW)                                                 \
    { float cn_ = (CN);                                                       \
      if (cn_ > 0.f)                                                          \
          atomicMin(&firstAcc[ROW], t0 + (int)((float)SEGLEN - (AF)));        \
      atomicAdd(&Cacc[ROW], cn_);                                             \
      atomicAdd(&tsAcc[ROW], fmaf((float)(t0 + SEGLEN), cn_, -(AS))); }
    TAIL(cnt4.x, accF4.x, accS4.x, row0)
    TAIL(cnt4.y, accF4.y, accS4.y, row0 + 64)
    TAIL(cnt4.z, accF4.z, accS4.z, row0 + 128)
    TAIL(cnt4.w, accF4.w, accS4.w, row0 + 192)
#undef TAIL
#undef DMA_CHUNK
}

__global__ __launch_bounds__(256) void fin_kernel(const float* __restrict__ Cacc,
                                                  const float* __restrict__ tsAcc,
                                                  const int* __restrict__ firstAcc,
                                                  float* __restrict__ out) {
    int r = blockIdx.x * 256 + threadIdx.x;
    if (r < B_DIM) {
        out[(size_t)B_DIM * L_DIM + r] = (float)firstAcc[r];
        out[(size_t)B_DIM * L_DIM + B_DIM + r] = tsAcc[r] / (Cacc[r] + 1e-6f);
    }
}

extern "C" void kernel_launch(void* const* d_in, const int* in_sizes, int n_in,
                              void* d_out, int out_size, void* d_ws, size_t ws_size,
                              hipStream_t stream) {
    const float* I = (const float*)d_in[0];
    float* out = (float*)d_out;
    float* wsf = (float*)d_ws;
    int* wsi = (int*)((float*)d_ws + 2 * B_DIM);
    (void)in_sizes; (void)n_in; (void)out_size; (void)ws_size;

    init_kernel<<<(2 * B_DIM + 255) / 256, 256, 0, stream>>>(wsf, wsi);
    lif_kernel<<<16 * NSEG, 64, 0, stream>>>(I, out, wsf, wsf + B_DIM, wsi);
    fin_kernel<<<(B_DIM + 255) / 256, 256, 0, stream>>>(wsf, wsf + B_DIM, wsi, out);
}